// Round 3
// baseline (1461.122 us; speedup 1.0000x reference)
//
#include <hip/hip_runtime.h>
#include <hip/hip_bf16.h>

#define N_NODES 100000
#define N_EDGES 1600000
#define D 128
#define N_TILES (N_NODES / 16)   // 6250, exact

typedef __bf16 bf16x8 __attribute__((ext_vector_type(8)));
typedef __bf16 bf16x4 __attribute__((ext_vector_type(4)));
typedef float  f32x4  __attribute__((ext_vector_type(4)));

// ------------- W transpose + cvt: W fp32 [k][n] -> WT bf16 [n][k] -------------
__global__ void transpose_w_kernel(const float* __restrict__ W,
                                   __bf16* __restrict__ WT) {
    int t = blockIdx.x * blockDim.x + threadIdx.x;   // 0..16383
    int k = t >> 7;
    int n = t & 127;
    WT[n * D + k] = (__bf16)W[t];
}

// ------------- GEMM: h = bf16(x) @ bf16(W) via mfma_f32_16x16x32_bf16 -------------
// wave handles one 16-row tile, all 128 cols (8 col-tiles), K=128 (4 k-steps)
__global__ __launch_bounds__(256) void gemm_kernel(
        const float* __restrict__ x,
        const __bf16* __restrict__ WT,
        __bf16* __restrict__ h) {
    const int wave = threadIdx.x >> 6;
    const int lane = threadIdx.x & 63;
    const int tile = blockIdx.x * 4 + wave;
    if (tile >= N_TILES) return;

    const int m    = lane & 15;
    const int quad = lane >> 4;

    const float* xp = x + (size_t)(tile * 16 + m) * D + quad * 8;

    f32x4 acc[8];
#pragma unroll
    for (int ct = 0; ct < 8; ++ct) acc[ct] = (f32x4)(0.0f);

#pragma unroll
    for (int kk = 0; kk < 4; ++kk) {
        f32x4 a0 = *(const f32x4*)(xp + kk * 32);
        f32x4 a1 = *(const f32x4*)(xp + kk * 32 + 4);
        bf16x8 a;
#pragma unroll
        for (int j = 0; j < 4; ++j) {
            a[j]     = (__bf16)a0[j];
            a[j + 4] = (__bf16)a1[j];
        }
#pragma unroll
        for (int ct = 0; ct < 8; ++ct) {
            bf16x8 b = *(const bf16x8*)(WT + (size_t)(ct * 16 + m) * D + kk * 32 + quad * 8);
            acc[ct] = __builtin_amdgcn_mfma_f32_16x16x32_bf16(a, b, acc[ct], 0, 0, 0);
        }
    }

    // C/D layout: col = lane&15, row = quad*4 + reg
#pragma unroll
    for (int ct = 0; ct < 8; ++ct) {
#pragma unroll
        for (int r = 0; r < 4; ++r) {
            int row = tile * 16 + quad * 4 + r;
            h[(size_t)row * D + ct * 16 + m] = (__bf16)acc[ct][r];
        }
    }
}

// ------------- SpMM: accum[row] += val * h[col], fp32 atomics -------------
// one wave per edge; lane covers 2 features (one 4B bf16x2 load)
__global__ __launch_bounds__(256) void spmm_kernel(
        const __bf16* __restrict__ h,
        const float* __restrict__ vals,
        const int* __restrict__ rows,
        const int* __restrict__ cols,
        float* __restrict__ accum) {
    const int e = blockIdx.x * 4 + (threadIdx.x >> 6);
    const int lane = threadIdx.x & 63;

    const int   r = rows[e];
    const int   c = cols[e];
    const float v = vals[e];

    unsigned int u = *((const unsigned int*)(h + (size_t)c * D) + lane);
    union { unsigned int i; float f; } lo, hi;
    lo.i = u << 16;
    hi.i = u & 0xffff0000u;

    float* op = accum + (size_t)r * D + lane * 2;
    unsafeAtomicAdd(op,     v * lo.f);
    unsafeAtomicAdd(op + 1, v * hi.f);
}

// ------------- epilogue: out = relu(accum), fp32 out -------------
__global__ __launch_bounds__(256) void relu_kernel(
        const float* __restrict__ accum,
        float* __restrict__ out) {
    int i = blockIdx.x * blockDim.x + threadIdx.x;   // one float4 per thread
    float4 val = ((const float4*)accum)[i];
    float4 o;
    o.x = fmaxf(val.x, 0.0f);
    o.y = fmaxf(val.y, 0.0f);
    o.z = fmaxf(val.z, 0.0f);
    o.w = fmaxf(val.w, 0.0f);
    ((float4*)out)[i] = o;
}

extern "C" void kernel_launch(void* const* d_in, const int* in_sizes, int n_in,
                              void* d_out, int out_size, void* d_ws, size_t ws_size,
                              hipStream_t stream) {
    const float* x    = (const float*)d_in[0];
    const float* w    = (const float*)d_in[1];
    const float* vals = (const float*)d_in[2];
    const int*   rows = (const int*)d_in[3];
    const int*   cols = (const int*)d_in[4];
    float*       out  = (float*)d_out;   // fp32 output, 51.2 MB

    float*  accum = (float*)d_ws;                                     // 51.2 MB
    __bf16* WT    = (__bf16*)((char*)d_ws + (size_t)N_NODES * D * 4); // +32 KB

    // zero the fp32 accumulator (ws is poisoned 0xAA before every launch)
    hipMemsetAsync(accum, 0, (size_t)N_NODES * D * sizeof(float), stream);

    // W^T (bf16) for vectorized MFMA B-fragment loads
    transpose_w_kernel<<<64, 256, 0, stream>>>(w, WT);

    // h = x @ W (bf16), staged in the FIRST HALF of d_out (25.6 MB of its 51.2 MB);
    // relu_kernel later overwrites all of d_out with fp32 results.
    __bf16* h = (__bf16*)d_out;
    gemm_kernel<<<(N_TILES + 3) / 4, 256, 0, stream>>>(x, WT, h);

    // scatter-add messages into fp32 accumulator
    spmm_kernel<<<N_EDGES / 4, 256, 0, stream>>>(h, vals, rows, cols, accum);

    // out = relu(accum), fp32
    relu_kernel<<<(N_NODES * D / 4) / 256, 256, 0, stream>>>(accum, out);
}

// Round 4
// 414.693 us; speedup vs baseline: 3.5234x; 3.5234x over previous
//
#include <hip/hip_runtime.h>
#include <hip/hip_bf16.h>

#define N_NODES 100000
#define N_EDGES 1600000
#define D 128
#define N_TILES (N_NODES / 16)        // 6250, exact
#define SCAN_BLOCKS 391               // 391*256 = 100096 >= N_NODES

typedef __bf16 bf16x8 __attribute__((ext_vector_type(8)));
typedef float  f32x4  __attribute__((ext_vector_type(4)));

// ------------- W transpose + cvt: W fp32 [k][n] -> WT bf16 [n][k] -------------
__global__ void transpose_w_kernel(const float* __restrict__ W,
                                   __bf16* __restrict__ WT) {
    int t = blockIdx.x * blockDim.x + threadIdx.x;   // 0..16383
    int k = t >> 7;
    int n = t & 127;
    WT[n * D + k] = (__bf16)W[t];
}

// ------------- GEMM: h = bf16(x) @ bf16(W) via mfma_f32_16x16x32_bf16 -------------
__global__ __launch_bounds__(256) void gemm_kernel(
        const float* __restrict__ x,
        const __bf16* __restrict__ WT,
        __bf16* __restrict__ h) {
    const int wave = threadIdx.x >> 6;
    const int lane = threadIdx.x & 63;
    const int tile = blockIdx.x * 4 + wave;
    if (tile >= N_TILES) return;

    const int m    = lane & 15;
    const int quad = lane >> 4;

    const float* xp = x + (size_t)(tile * 16 + m) * D + quad * 8;

    f32x4 acc[8];
#pragma unroll
    for (int ct = 0; ct < 8; ++ct) acc[ct] = (f32x4)(0.0f);

#pragma unroll
    for (int kk = 0; kk < 4; ++kk) {
        f32x4 a0 = *(const f32x4*)(xp + kk * 32);
        f32x4 a1 = *(const f32x4*)(xp + kk * 32 + 4);
        bf16x8 a;
#pragma unroll
        for (int j = 0; j < 4; ++j) {
            a[j]     = (__bf16)a0[j];
            a[j + 4] = (__bf16)a1[j];
        }
#pragma unroll
        for (int ct = 0; ct < 8; ++ct) {
            bf16x8 b = *(const bf16x8*)(WT + (size_t)(ct * 16 + m) * D + kk * 32 + quad * 8);
            acc[ct] = __builtin_amdgcn_mfma_f32_16x16x32_bf16(a, b, acc[ct], 0, 0, 0);
        }
    }

#pragma unroll
    for (int ct = 0; ct < 8; ++ct) {
#pragma unroll
        for (int r = 0; r < 4; ++r) {
            int row = tile * 16 + quad * 4 + r;
            h[(size_t)row * D + ct * 16 + m] = (__bf16)acc[ct][r];
        }
    }
}

// ------------- counting sort: histogram of edge rows -------------
__global__ __launch_bounds__(256) void hist_kernel(const int* __restrict__ rows,
                                                   int* __restrict__ counts) {
    int e = blockIdx.x * 256 + threadIdx.x;
    atomicAdd(&counts[rows[e]], 1);
}

// ------------- scan pass 1: per-block (256-elem) reduction -------------
__global__ __launch_bounds__(256) void block_reduce_kernel(const int* __restrict__ counts,
                                                           int* __restrict__ blockSums) {
    int i = blockIdx.x * 256 + threadIdx.x;
    int v = (i < N_NODES) ? counts[i] : 0;
#pragma unroll
    for (int off = 32; off; off >>= 1) v += __shfl_down(v, off, 64);
    __shared__ int sm[4];
    if ((threadIdx.x & 63) == 0) sm[threadIdx.x >> 6] = v;
    __syncthreads();
    if (threadIdx.x == 0) blockSums[blockIdx.x] = sm[0] + sm[1] + sm[2] + sm[3];
}

// ------------- scan pass 2: exclusive scan of block sums (1 block) -------------
__global__ __launch_bounds__(512) void scan_blocksums_kernel(int* __restrict__ blockSums) {
    __shared__ int sm[512];
    int v = (threadIdx.x < SCAN_BLOCKS) ? blockSums[threadIdx.x] : 0;
    sm[threadIdx.x] = v;
    __syncthreads();
    for (int d = 1; d < 512; d <<= 1) {
        int t = (threadIdx.x >= (unsigned)d) ? sm[threadIdx.x - d] : 0;
        __syncthreads();
        sm[threadIdx.x] += t;
        __syncthreads();
    }
    if (threadIdx.x < SCAN_BLOCKS) blockSums[threadIdx.x] = sm[threadIdx.x] - v; // exclusive
}

// ------------- scan pass 3: per-block exclusive scan + block offset -------------
__global__ __launch_bounds__(256) void scan_final_kernel(const int* __restrict__ counts,
                                                         const int* __restrict__ blockSums,
                                                         int* __restrict__ offsets,
                                                         int* __restrict__ cursor) {
    __shared__ int sm[256];
    int i = blockIdx.x * 256 + threadIdx.x;
    int v = (i < N_NODES) ? counts[i] : 0;
    sm[threadIdx.x] = v;
    __syncthreads();
    for (int d = 1; d < 256; d <<= 1) {
        int t = (threadIdx.x >= (unsigned)d) ? sm[threadIdx.x - d] : 0;
        __syncthreads();
        sm[threadIdx.x] += t;
        __syncthreads();
    }
    if (i < N_NODES) {
        int excl = sm[threadIdx.x] - v + blockSums[blockIdx.x];
        offsets[i] = excl;
        cursor[i]  = excl;
    }
}

// ------------- scatter edges into row-sorted order -------------
__global__ __launch_bounds__(256) void scatter_kernel(const int* __restrict__ rows,
                                                      const int* __restrict__ cols,
                                                      const float* __restrict__ vals,
                                                      int* __restrict__ cursor,
                                                      int* __restrict__ scol,
                                                      float* __restrict__ sval) {
    int e = blockIdx.x * 256 + threadIdx.x;
    int r = rows[e];
    int pos = atomicAdd(&cursor[r], 1);
    scol[pos] = cols[e];
    sval[pos] = vals[e];
}

// ------------- segmented sum + relu, fused output write -------------
// one wave per row; lane covers 2 features (one 4B bf16x2 gather per edge)
__global__ __launch_bounds__(256) void segsum_kernel(const __bf16* __restrict__ h,
                                                     const int* __restrict__ offsets,
                                                     const int* __restrict__ cursor,
                                                     const int* __restrict__ scol,
                                                     const float* __restrict__ sval,
                                                     float* __restrict__ out) {
    const int r    = blockIdx.x * 4 + (threadIdx.x >> 6);   // grid covers exactly N_NODES
    const int lane = threadIdx.x & 63;

    const int start = offsets[r];
    const int end   = cursor[r];    // post-scatter: offsets[r] + count[r]

    float a0 = 0.0f, b0 = 0.0f;     // lane's 2 features, 2-way unrolled accumulators
    float a1 = 0.0f, b1 = 0.0f;

    int i = start;
    for (; i + 1 < end; i += 2) {
        int   c0 = scol[i],     c1 = scol[i + 1];
        float v0 = sval[i],     v1 = sval[i + 1];
        unsigned u0 = *((const unsigned*)(h + (size_t)c0 * D) + lane);
        unsigned u1 = *((const unsigned*)(h + (size_t)c1 * D) + lane);
        union { unsigned i; float f; } lo0, hi0, lo1, hi1;
        lo0.i = u0 << 16; hi0.i = u0 & 0xffff0000u;
        lo1.i = u1 << 16; hi1.i = u1 & 0xffff0000u;
        a0 += v0 * lo0.f; b0 += v0 * hi0.f;
        a1 += v1 * lo1.f; b1 += v1 * hi1.f;
    }
    if (i < end) {
        int   c0 = scol[i];
        float v0 = sval[i];
        unsigned u0 = *((const unsigned*)(h + (size_t)c0 * D) + lane);
        union { unsigned i; float f; } lo0, hi0;
        lo0.i = u0 << 16; hi0.i = u0 & 0xffff0000u;
        a0 += v0 * lo0.f; b0 += v0 * hi0.f;
    }

    float* op = out + (size_t)r * D + lane * 2;
    op[0] = fmaxf(a0 + a1, 0.0f);
    op[1] = fmaxf(b0 + b1, 0.0f);
}

extern "C" void kernel_launch(void* const* d_in, const int* in_sizes, int n_in,
                              void* d_out, int out_size, void* d_ws, size_t ws_size,
                              hipStream_t stream) {
    const float* x    = (const float*)d_in[0];
    const float* w    = (const float*)d_in[1];
    const float* vals = (const float*)d_in[2];
    const int*   rows = (const int*)d_in[3];
    const int*   cols = (const int*)d_in[4];
    float*       out  = (float*)d_out;   // fp32, 51.2 MB

    // ---- workspace carve-up (~39.3 MB; R3 proved >= 51.2 MB available) ----
    char* p = (char*)d_ws;
    __bf16* h         = (__bf16*)p;                 p += (size_t)N_NODES * D * 2;   // 25.6 MB
    __bf16* WT        = (__bf16*)p;                 p += (size_t)D * D * 2;         // 32 KB
    int*    counts    = (int*)p;                    p += (size_t)N_NODES * 4;       // 400 KB
    int*    offsets   = (int*)p;                    p += (size_t)N_NODES * 4;       // 400 KB
    int*    cursor    = (int*)p;                    p += (size_t)N_NODES * 4;       // 400 KB
    int*    blockSums = (int*)p;                    p += 4096;                      // 1.6 KB used
    int*    scol      = (int*)p;                    p += (size_t)N_EDGES * 4;       // 6.4 MB
    float*  sval      = (float*)p;                  p += (size_t)N_EDGES * 4;       // 6.4 MB

    // zero histogram counters (ws is poisoned 0xAA before every timed call)
    hipMemsetAsync(counts, 0, (size_t)N_NODES * sizeof(int), stream);

    // W^T (bf16) for vectorized MFMA B-fragment loads
    transpose_w_kernel<<<64, 256, 0, stream>>>(w, WT);

    // h = x @ W (bf16) into ws
    gemm_kernel<<<(N_TILES + 3) / 4, 256, 0, stream>>>(x, WT, h);

    // counting sort of edges by destination row
    hist_kernel<<<N_EDGES / 256, 256, 0, stream>>>(rows, counts);
    block_reduce_kernel<<<SCAN_BLOCKS, 256, 0, stream>>>(counts, blockSums);
    scan_blocksums_kernel<<<1, 512, 0, stream>>>(blockSums);
    scan_final_kernel<<<SCAN_BLOCKS, 256, 0, stream>>>(counts, blockSums, offsets, cursor);
    scatter_kernel<<<N_EDGES / 256, 256, 0, stream>>>(rows, cols, vals, cursor, scol, sval);

    // per-row register-space reduction, fused relu, direct fp32 output
    segsum_kernel<<<N_NODES / 4, 256, 0, stream>>>(h, offsets, cursor, scol, sval, out);
}

// Round 6
// 398.495 us; speedup vs baseline: 3.6666x; 1.0406x over previous
//
#include <hip/hip_runtime.h>
#include <hip/hip_bf16.h>

#define N_NODES 100000
#define N_EDGES 1600000
#define D 128
#define N_TILES (N_NODES / 16)        // 6250, exact
#define SCAN_BLOCKS 391               // 391*256 = 100096 >= N_NODES
#define LPAD 144                      // LDS row stride (bf16 elems): 144*2B=288B -> bank-offset 8/quad

typedef __bf16 bf16x8 __attribute__((ext_vector_type(8)));
typedef float  f32x4  __attribute__((ext_vector_type(4)));
typedef float  f32x2  __attribute__((ext_vector_type(2)));

// ------------- W transpose + cvt: W fp32 [k][n] -> WT bf16 [n][k] -------------
__global__ void transpose_w_kernel(const float* __restrict__ W,
                                   __bf16* __restrict__ WT) {
    int t = blockIdx.x * blockDim.x + threadIdx.x;   // 0..16383
    int k = t >> 7;
    int n = t & 127;
    WT[n * D + k] = (__bf16)W[t];
}

// ------------- GEMM: h = bf16(x) @ bf16(W) via mfma_f32_16x16x32_bf16 -------------
// wave handles one 16-row tile; epilogue goes through wave-private LDS so the
// global h-store is 16B/lane fully-coalesced (4 complete 256B rows per instr).
__global__ __launch_bounds__(256) void gemm_kernel(
        const float* __restrict__ x,
        const __bf16* __restrict__ WT,
        __bf16* __restrict__ h) {
    __shared__ __bf16 lsm[4][16][LPAD];   // 18.4 KB
    const int wave = threadIdx.x >> 6;
    const int lane = threadIdx.x & 63;
    const int tile = blockIdx.x * 4 + wave;
    if (tile >= N_TILES) return;

    const int m    = lane & 15;
    const int quad = lane >> 4;

    const float* xp = x + (size_t)(tile * 16 + m) * D + quad * 8;

    f32x4 acc[8];
#pragma unroll
    for (int ct = 0; ct < 8; ++ct) acc[ct] = (f32x4)(0.0f);

#pragma unroll
    for (int kk = 0; kk < 4; ++kk) {
        f32x4 a0 = *(const f32x4*)(xp + kk * 32);
        f32x4 a1 = *(const f32x4*)(xp + kk * 32 + 4);
        bf16x8 a;
#pragma unroll
        for (int j = 0; j < 4; ++j) {
            a[j]     = (__bf16)a0[j];
            a[j + 4] = (__bf16)a1[j];
        }
#pragma unroll
        for (int ct = 0; ct < 8; ++ct) {
            bf16x8 b = *(const bf16x8*)(WT + (size_t)(ct * 16 + m) * D + kk * 32 + quad * 8);
            acc[ct] = __builtin_amdgcn_mfma_f32_16x16x32_bf16(a, b, acc[ct], 0, 0, 0);
        }
    }

    // C/D layout: col = ct*16 + (lane&15), row_local = quad*4 + r
#pragma unroll
    for (int ct = 0; ct < 8; ++ct)
#pragma unroll
        for (int r = 0; r < 4; ++r)
            lsm[wave][quad * 4 + r][ct * 16 + m] = (__bf16)acc[ct][r];

    // wave-private region: compiler inserts lgkmcnt wait for the RAW dependence
#pragma unroll
    for (int i = 0; i < 4; ++i) {
        int rl = i * 4 + quad;
        bf16x8 vv = *(const bf16x8*)&lsm[wave][rl][m * 8];
        *(bf16x8*)(h + (size_t)(tile * 16 + rl) * D + m * 8) = vv;
    }
}

// ------------- counting sort: histogram of edge rows -------------
__global__ __launch_bounds__(256) void hist_kernel(const int* __restrict__ rows,
                                                   int* __restrict__ counts) {
    int e = blockIdx.x * 256 + threadIdx.x;
    atomicAdd(&counts[rows[e]], 1);
}

// ------------- scan pass 1: per-block (256-elem) reduction -------------
__global__ __launch_bounds__(256) void block_reduce_kernel(const int* __restrict__ counts,
                                                           int* __restrict__ blockSums) {
    int i = blockIdx.x * 256 + threadIdx.x;
    int v = (i < N_NODES) ? counts[i] : 0;
#pragma unroll
    for (int off = 32; off; off >>= 1) v += __shfl_down(v, off, 64);
    __shared__ int sm[4];
    if ((threadIdx.x & 63) == 0) sm[threadIdx.x >> 6] = v;
    __syncthreads();
    if (threadIdx.x == 0) blockSums[blockIdx.x] = sm[0] + sm[1] + sm[2] + sm[3];
}

// ------------- scan pass 2: exclusive scan of block sums (1 block) -------------
__global__ __launch_bounds__(512) void scan_blocksums_kernel(int* __restrict__ blockSums) {
    __shared__ int sm[512];
    int v = (threadIdx.x < SCAN_BLOCKS) ? blockSums[threadIdx.x] : 0;
    sm[threadIdx.x] = v;
    __syncthreads();
    for (int d = 1; d < 512; d <<= 1) {
        int t = (threadIdx.x >= (unsigned)d) ? sm[threadIdx.x - d] : 0;
        __syncthreads();
        sm[threadIdx.x] += t;
        __syncthreads();
    }
    if (threadIdx.x < SCAN_BLOCKS) blockSums[threadIdx.x] = sm[threadIdx.x] - v; // exclusive
}

// ------------- scan pass 3: per-block exclusive scan + block offset -------------
__global__ __launch_bounds__(256) void scan_final_kernel(const int* __restrict__ counts,
                                                         const int* __restrict__ blockSums,
                                                         int* __restrict__ offsets,
                                                         int* __restrict__ cursor) {
    __shared__ int sm[256];
    int i = blockIdx.x * 256 + threadIdx.x;
    int v = (i < N_NODES) ? counts[i] : 0;
    sm[threadIdx.x] = v;
    __syncthreads();
    for (int d = 1; d < 256; d <<= 1) {
        int t = (threadIdx.x >= (unsigned)d) ? sm[threadIdx.x - d] : 0;
        __syncthreads();
        sm[threadIdx.x] += t;
        __syncthreads();
    }
    if (i < N_NODES) {
        int excl = sm[threadIdx.x] - v + blockSums[blockIdx.x];
        offsets[i] = excl;
        cursor[i]  = excl;
    }
}

// ------------- scatter edges into row-sorted order, (col,val) packed 8B -------------
__global__ __launch_bounds__(256) void scatter_kernel(const int* __restrict__ rows,
                                                      const int* __restrict__ cols,
                                                      const float* __restrict__ vals,
                                                      int* __restrict__ cursor,
                                                      int2* __restrict__ svc) {
    int e = blockIdx.x * 256 + threadIdx.x;
    int r = rows[e];
    int pos = atomicAdd(&cursor[r], 1);
    int2 pk;
    pk.x = cols[e];
    pk.y = __float_as_int(vals[e]);
    svc[pos] = pk;
}

// ------------- segmented sum + relu, 4-way unrolled for MLP -------------
// one wave per row; lane covers 2 features (one 4B bf16x2 gather per edge)
__global__ __launch_bounds__(256) void segsum_kernel(const __bf16* __restrict__ h,
                                                     const int* __restrict__ offsets,
                                                     const int* __restrict__ cursor,
                                                     const int2* __restrict__ svc,
                                                     float* __restrict__ out) {
    const int r    = blockIdx.x * 4 + (threadIdx.x >> 6);   // grid covers exactly N_NODES
    const int lane = threadIdx.x & 63;

    const int start = offsets[r];
    const int end   = cursor[r];    // post-scatter: offsets[r] + count[r]

    float a0 = 0.f, b0 = 0.f, a1 = 0.f, b1 = 0.f;
    float a2 = 0.f, b2 = 0.f, a3 = 0.f, b3 = 0.f;

    int i = start;
    for (; i + 3 < end; i += 4) {
        int2 e0 = svc[i], e1 = svc[i + 1], e2 = svc[i + 2], e3 = svc[i + 3];
        unsigned u0 = *((const unsigned*)(h + (size_t)e0.x * D) + lane);
        unsigned u1 = *((const unsigned*)(h + (size_t)e1.x * D) + lane);
        unsigned u2 = *((const unsigned*)(h + (size_t)e2.x * D) + lane);
        unsigned u3 = *((const unsigned*)(h + (size_t)e3.x * D) + lane);
        float v0 = __int_as_float(e0.y), v1 = __int_as_float(e1.y);
        float v2 = __int_as_float(e2.y), v3 = __int_as_float(e3.y);
        a0 += v0 * __int_as_float(u0 << 16);  b0 += v0 * __int_as_float(u0 & 0xffff0000u);
        a1 += v1 * __int_as_float(u1 << 16);  b1 += v1 * __int_as_float(u1 & 0xffff0000u);
        a2 += v2 * __int_as_float(u2 << 16);  b2 += v2 * __int_as_float(u2 & 0xffff0000u);
        a3 += v3 * __int_as_float(u3 << 16);  b3 += v3 * __int_as_float(u3 & 0xffff0000u);
    }
    for (; i < end; ++i) {
        int2 e0 = svc[i];
        unsigned u0 = *((const unsigned*)(h + (size_t)e0.x * D) + lane);
        float v0 = __int_as_float(e0.y);
        a0 += v0 * __int_as_float(u0 << 16);  b0 += v0 * __int_as_float(u0 & 0xffff0000u);
    }

    f32x2 o;
    o[0] = fmaxf((a0 + a1) + (a2 + a3), 0.0f);
    o[1] = fmaxf((b0 + b1) + (b2 + b3), 0.0f);
    __builtin_nontemporal_store(o, (f32x2*)(out + (size_t)r * D + lane * 2));
}

extern "C" void kernel_launch(void* const* d_in, const int* in_sizes, int n_in,
                              void* d_out, int out_size, void* d_ws, size_t ws_size,
                              hipStream_t stream) {
    const float* x    = (const float*)d_in[0];
    const float* w    = (const float*)d_in[1];
    const float* vals = (const float*)d_in[2];
    const int*   rows = (const int*)d_in[3];
    const int*   cols = (const int*)d_in[4];
    float*       out  = (float*)d_out;   // fp32, 51.2 MB

    // ---- workspace carve-up (~39.3 MB) ----
    char* p = (char*)d_ws;
    __bf16* h         = (__bf16*)p;                 p += (size_t)N_NODES * D * 2;   // 25.6 MB
    __bf16* WT        = (__bf16*)p;                 p += (size_t)D * D * 2;         // 32 KB
    int*    counts    = (int*)p;                    p += (size_t)N_NODES * 4;       // 400 KB
    int*    offsets   = (int*)p;                    p += (size_t)N_NODES * 4;       // 400 KB
    int*    cursor    = (int*)p;                    p += (size_t)N_NODES * 4;       // 400 KB
    int*    blockSums = (int*)p;                    p += 4096;                      // 1.6 KB used
    int2*   svc       = (int2*)p;                   p += (size_t)N_EDGES * 8;       // 12.8 MB

    // zero histogram counters (ws is poisoned 0xAA before every timed call)
    (void)hipMemsetAsync(counts, 0, (size_t)N_NODES * sizeof(int), stream);

    // W^T (bf16) for vectorized MFMA B-fragment loads
    transpose_w_kernel<<<64, 256, 0, stream>>>(w, WT);

    // h = x @ W (bf16) into ws
    gemm_kernel<<<(N_TILES + 3) / 4, 256, 0, stream>>>(x, WT, h);

    // counting sort of edges by destination row
    hist_kernel<<<N_EDGES / 256, 256, 0, stream>>>(rows, counts);
    block_reduce_kernel<<<SCAN_BLOCKS, 256, 0, stream>>>(counts, blockSums);
    scan_blocksums_kernel<<<1, 512, 0, stream>>>(blockSums);
    scan_final_kernel<<<SCAN_BLOCKS, 256, 0, stream>>>(counts, blockSums, offsets, cursor);
    scatter_kernel<<<N_EDGES / 256, 256, 0, stream>>>(rows, cols, vals, cursor, svc);

    // per-row register-space reduction, fused relu, direct fp32 output
    segsum_kernel<<<N_NODES / 4, 256, 0, stream>>>(h, offsets, cursor, svc, out);
}